// Round 8
// baseline (384.435 us; speedup 1.0000x reference)
//
#include <hip/hip_runtime.h>
#include <stdint.h>

#define D_DIM 1024
#define N_DIM 65536
#define Q_DIM 2048
#define K_DIM 3

#define NBLK  256            // one block per CU
#define TPB   1024           // 16 waves
#define NSP   4              // stage-passes: 64 cols (256 B) each
#define NSLAB 16             // slabs per stage-pass (64 rows each)
#define NGS   64             // total slabs

// LDS map (dynamic):
#define RING_OFF  0          // 4 x 16384 B raw slab slots (64 rows x 256 B)
#define SCR_OFF   65536      // denominator scratch, 2 x 4096 B (slab-parity dbuf)
#define TAB_OFF   73728      // bf16 table [1024 rows][32 cols] = 65536 B, granule-swizzled
#define LDS_TOTAL 139264

#define VMCNT3() asm volatile("s_waitcnt vmcnt(3)" ::: "memory")
#define VMCNT2() asm volatile("s_waitcnt vmcnt(2)" ::: "memory")
#define VMCNT1() asm volatile("s_waitcnt vmcnt(1)" ::: "memory")
#define VMCNT0() asm volatile("s_waitcnt vmcnt(0)" ::: "memory")
#define LGKM0()  asm volatile("s_waitcnt lgkmcnt(0)" ::: "memory")
#define SCHED0() __builtin_amdgcn_sched_barrier(0)
#define SBAR()   __builtin_amdgcn_s_barrier()

typedef const __attribute__((address_space(1))) uint32_t  glb_u32;
typedef __attribute__((address_space(3))) uint32_t        lds_u32;

// round-to-nearest-even f32 -> bf16 (positive normal probs)
__device__ __forceinline__ uint32_t f2bf(float f) {
    uint32_t u = __float_as_uint(f);
    return (u + 0x7fffu + ((u >> 16) & 1u)) >> 16;
}
__device__ __forceinline__ float blo(uint32_t u) { return __uint_as_float(u << 16); }
__device__ __forceinline__ float bhi(uint32_t u) { return __uint_as_float(u & 0xffff0000u); }

// DMA one slab (64 rows x 256 B) into ring slot gs&3. ONE inst per wave:
// 64 lanes x 16 B = 4 rows x FULL 256-B span (2 whole HBM lines per row,
// adjacent) -- 256-B segments, half the segment count of R5 at 2x length.
// Raw buffer granule-swizzled (key row&3) via pre-swizzled GLOBAL source;
// LDS dest stays linear (wave-uniform base + lane*16).
__device__ __forceinline__ void stage_slab(const float* __restrict__ W, char* smem,
                                           int gs, int bid, int w, int l) {
    const int sp  = gs >> 4, s = gs & 15;
    const int row = (s << 6) + (w << 2) + (l >> 4);            // global row 0..1023
    const int srcg = ((l & 15) ^ ((l >> 4) & 3)) << 4;         // swizzled 16-B granule
    const char* src = (const char*)W + ((size_t)row << 18)
                      + bid * 1024 + sp * 256 + srcg;
    __builtin_amdgcn_global_load_lds((glb_u32*)src,
        (lds_u32*)(smem + RING_OFF + ((gs & 3) << 14) + (w << 10) + (l << 4)), 16, 0, 0);
}

// compute phase: 2 queries x 4 granules x 8 cols (verbatim R5 layout)
#define COMPUTE_PHASE()                                                                           \
    _Pragma("unroll")                                                                             \
    for (int g16 = 0; g16 < 4; ++g16) {                                                           \
        const int gb = g16 << 4;                                                                  \
        {                                                                                         \
            const uint4 va = *(const uint4*)(smem + TAB_OFF + baseb[0][0] + (gb ^ swzb[0][0]));   \
            const uint4 vb = *(const uint4*)(smem + TAB_OFF + baseb[0][1] + (gb ^ swzb[0][1]));   \
            const uint4 vc = *(const uint4*)(smem + TAB_OFF + baseb[0][2] + (gb ^ swzb[0][2]));   \
            acc0 = fmaf(blo(va.x) * blo(vb.x), blo(vc.x), acc0);                                  \
            acc0 = fmaf(bhi(va.x) * bhi(vb.x), bhi(vc.x), acc0);                                  \
            acc0 = fmaf(blo(va.y) * blo(vb.y), blo(vc.y), acc0);                                  \
            acc0 = fmaf(bhi(va.y) * bhi(vb.y), bhi(vc.y), acc0);                                  \
            acc0 = fmaf(blo(va.z) * blo(vb.z), blo(vc.z), acc0);                                  \
            acc0 = fmaf(bhi(va.z) * bhi(vb.z), bhi(vc.z), acc0);                                  \
            acc0 = fmaf(blo(va.w) * blo(vb.w), blo(vc.w), acc0);                                  \
            acc0 = fmaf(bhi(va.w) * bhi(vb.w), bhi(vc.w), acc0);                                  \
        }                                                                                         \
        {                                                                                         \
            const uint4 va = *(const uint4*)(smem + TAB_OFF + baseb[1][0] + (gb ^ swzb[1][0]));   \
            const uint4 vb = *(const uint4*)(smem + TAB_OFF + baseb[1][1] + (gb ^ swzb[1][1]));   \
            const uint4 vc = *(const uint4*)(smem + TAB_OFF + baseb[1][2] + (gb ^ swzb[1][2]));   \
            acc1 = fmaf(blo(va.x) * blo(vb.x), blo(vc.x), acc1);                                  \
            acc1 = fmaf(bhi(va.x) * bhi(vb.x), bhi(vc.x), acc1);                                  \
            acc1 = fmaf(blo(va.y) * blo(vb.y), blo(vc.y), acc1);                                  \
            acc1 = fmaf(bhi(va.y) * bhi(vb.y), bhi(vc.y), acc1);                                  \
            acc1 = fmaf(blo(va.z) * blo(vb.z), blo(vc.z), acc1);                                  \
            acc1 = fmaf(bhi(va.z) * bhi(vb.z), bhi(vc.z), acc1);                                  \
            acc1 = fmaf(blo(va.w) * blo(vb.w), blo(vc.w), acc1);                                  \
            acc1 = fmaf(bhi(va.w) * bhi(vb.w), bhi(vc.w), acc1);                                  \
        }                                                                                         \
    }

template<bool ATOMIC>
__global__ __launch_bounds__(TPB, 4) void rap_main(const float* __restrict__ W,
                                                   const int* __restrict__ qidx,
                                                   float* __restrict__ outp) {
    extern __shared__ char smem[];
    const int tid = threadIdx.x;
    const int bid = blockIdx.x;
    const int w = tid >> 6, l = tid & 63;

    // ---- per-thread query constants (2 queries/thread) ----
    const int q0 = tid * 2;
    int baseb[2][K_DIM];   // d*64 : byte base of table row
    int swzb[2][K_DIM];    // ((d>>1)&3)<<4 : granule XOR key in bytes
#pragma unroll
    for (int qq = 0; qq < 2; ++qq) {
#pragma unroll
        for (int k = 0; k < K_DIM; ++k) {
            const int d = qidx[(q0 + qq) * K_DIM + k];
            baseb[qq][k] = d << 6;
            swzb[qq][k]  = ((d >> 1) & 3) << 4;
        }
    }

    // ---- processing mapping: thread -> (slab-local row, col-pair) ----
    const int rl  = tid >> 4;        // 0..63  (staged by wave rl>>2 == own wave)
    const int cp  = tid & 15;        // col-pair 0..15
    const int key = rl & 3;          // raw granule swizzle key
    const int gl  = tid >> 8;        // group-local = w>>2 (softmax group within slab)

    float acc0 = 0.f, acc1 = 0.f;
    uint32_t held[16];

    // drain setup loads so vmcnt counts only stage DMAs; fill ring
    VMCNT0(); SCHED0();
    stage_slab(W, smem, 0, bid, w, l);
    stage_slab(W, smem, 1, bid, w, l);
    stage_slab(W, smem, 2, bid, w, l);
    stage_slab(W, smem, 3, bid, w, l);

    for (int sp = 0; sp < NSP; ++sp) {
#pragma unroll
        for (int s = 0; s < NSLAB; ++s) {
            const int gs  = sp * NSLAB + s;
            const int rem = (NGS - 1) - gs;
            if (rem >= 3)      { VMCNT3(); }
            else if (rem == 2) { VMCNT2(); }
            else if (rem == 1) { VMCNT1(); }
            else               { VMCNT0(); }
            SCHED0();

            const int par  = gs & 1;
            const char* rowb = smem + RING_OFF + ((gs & 3) << 14) + rl * 256;

            // raw reads: 2 table cols + 2 held cols (wave-local rows)
            const int giT = cp >> 1;
            const uint2 rT = *(const uint2*)(rowb + ((giT ^ key) << 4) + ((cp & 1) << 3));
            const uint2 rH = *(const uint2*)(rowb + (((8 + giT) ^ key) << 4) + ((cp & 1) << 3));
            const float eT0 = __expf(__uint_as_float(rT.x));
            const float eT1 = __expf(__uint_as_float(rT.y));
            const float eH0 = __expf(__uint_as_float(rH.x));
            const float eH1 = __expf(__uint_as_float(rH.y));

            // in-wave 4-row partial sums (wave's 4 rows are in one group)
            float s0 = eT0, s1 = eT1, s2 = eH0, s3 = eH1;
            s0 += __shfl_xor(s0, 16); s1 += __shfl_xor(s1, 16);
            s2 += __shfl_xor(s2, 16); s3 += __shfl_xor(s3, 16);
            s0 += __shfl_xor(s0, 32); s1 += __shfl_xor(s1, 32);
            s2 += __shfl_xor(s2, 32); s3 += __shfl_xor(s3, 32);
            if (l < 16)
                *(float4*)(smem + SCR_OFF + par * 4096 + gl * 1024 + (w & 3) * 256 + cp * 16)
                    = make_float4(s0, s1, s2, s3);
            LGKM0(); SCHED0(); SBAR(); SCHED0();

            // cross-wave combine: 4 sub-wave partials of this thread's group
            const float4 p0 = *(const float4*)(smem + SCR_OFF + par * 4096 + gl * 1024 + 0 * 256 + cp * 16);
            const float4 p1 = *(const float4*)(smem + SCR_OFF + par * 4096 + gl * 1024 + 1 * 256 + cp * 16);
            const float4 p2 = *(const float4*)(smem + SCR_OFF + par * 4096 + gl * 1024 + 2 * 256 + cp * 16);
            const float4 p3 = *(const float4*)(smem + SCR_OFF + par * 4096 + gl * 1024 + 3 * 256 + cp * 16);
            const float rT0 = __builtin_amdgcn_rcpf(p0.x + p1.x + p2.x + p3.x);
            const float rT1 = __builtin_amdgcn_rcpf(p0.y + p1.y + p2.y + p3.y);
            const float rH0 = __builtin_amdgcn_rcpf(p0.z + p1.z + p2.z + p3.z);
            const float rH1 = __builtin_amdgcn_rcpf(p0.w + p1.w + p2.w + p3.w);

            // pack: table macro written now, held macro kept in regs
            const int rg = (s << 6) + rl;   // table row
            *(uint32_t*)(smem + TAB_OFF + rg * 64
                         + (((cp >> 2) ^ ((rg >> 1) & 3)) << 4) + ((cp & 3) << 2))
                = f2bf(eT0 * rT0) | (f2bf(eT1 * rT1) << 16);
            held[s] = f2bf(eH0 * rH0) | (f2bf(eH1 * rH1) << 16);

            // refill ring slot (raw reads retired at the LGKM0 above)
            if (gs + 4 < NGS) stage_slab(W, smem, gs + 4, bid, w, l);
            SCHED0();
        }

        LGKM0(); SCHED0(); SBAR(); SCHED0();   // table macro published
        COMPUTE_PHASE();
        LGKM0(); SCHED0(); SBAR(); SCHED0();   // table consumed

        // dump held macro into table
#pragma unroll
        for (int s2 = 0; s2 < NSLAB; ++s2) {
            const int rg = (s2 << 6) + rl;
            *(uint32_t*)(smem + TAB_OFF + rg * 64
                         + (((cp >> 2) ^ ((rg >> 1) & 3)) << 4) + ((cp & 3) << 2)) = held[s2];
        }
        LGKM0(); SCHED0(); SBAR(); SCHED0();   // held macro published
        COMPUTE_PHASE();
        LGKM0(); SCHED0(); SBAR(); SCHED0();   // table free for next sp
    }

    if (ATOMIC) {
        atomicAdd(outp + q0,     acc0 * (1.0f / N_DIM));
        atomicAdd(outp + q0 + 1, acc1 * (1.0f / N_DIM));
    } else {
        outp[(size_t)bid * Q_DIM + q0]     = acc0;
        outp[(size_t)bid * Q_DIM + q0 + 1] = acc1;
    }
}

__global__ __launch_bounds__(256) void rap_reduce(const float* __restrict__ partials,
                                                  float* __restrict__ outp) {
    const int q = blockIdx.x * blockDim.x + threadIdx.x;
    float s0 = 0.f, s1 = 0.f, s2 = 0.f, s3 = 0.f;
#pragma unroll 4
    for (int b = 0; b < NBLK; b += 4) {
        s0 += partials[(size_t)(b + 0) * Q_DIM + q];
        s1 += partials[(size_t)(b + 1) * Q_DIM + q];
        s2 += partials[(size_t)(b + 2) * Q_DIM + q];
        s3 += partials[(size_t)(b + 3) * Q_DIM + q];
    }
    outp[q] = ((s0 + s1) + (s2 + s3)) * (1.0f / N_DIM);
}

extern "C" void kernel_launch(void* const* d_in, const int* in_sizes, int n_in,
                              void* d_out, int out_size, void* d_ws, size_t ws_size,
                              hipStream_t stream) {
    const float* W    = (const float*)d_in[0];
    const int*   qidx = (const int*)d_in[1];
    float*       outp = (float*)d_out;

    const size_t need = (size_t)NBLK * Q_DIM * sizeof(float);
    if (ws_size >= need) {
        (void)hipFuncSetAttribute((const void*)rap_main<false>,
                                  hipFuncAttributeMaxDynamicSharedMemorySize, LDS_TOTAL);
        float* partials = (float*)d_ws;
        hipLaunchKernelGGL(rap_main<false>, dim3(NBLK), dim3(TPB), LDS_TOTAL, stream,
                           W, qidx, partials);
        hipLaunchKernelGGL(rap_reduce, dim3(Q_DIM / 256), dim3(256), 0, stream,
                           partials, outp);
    } else {
        (void)hipFuncSetAttribute((const void*)rap_main<true>,
                                  hipFuncAttributeMaxDynamicSharedMemorySize, LDS_TOTAL);
        (void)hipMemsetAsync(d_out, 0, Q_DIM * sizeof(float), stream);
        hipLaunchKernelGGL(rap_main<true>, dim3(NBLK), dim3(TPB), LDS_TOTAL, stream,
                           W, qidx, outp);
    }
}

// Round 9
// 66.162 us; speedup vs baseline: 5.8105x; 5.8105x over previous
//
#include <hip/hip_runtime.h>
#include <stdint.h>

#define D_DIM 1024
#define N_DIM 65536
#define Q_DIM 2048
#define K_DIM 3

#define NBLK  256            // one block per CU
#define TPB   1024           // 16 waves
#define MACW  32             // cols per macro (compute granularity)
#define NMAC  8              // macros per block -> 256 cols
#define NQT   32             // total stage-quarters (NMAC * 4)
#define QROWS 256            // quarter = 256 rows x 128 B = 32 KB

// LDS map (dynamic): ring 3 x 32 KB + table 64 KB = exactly 160 KiB
#define RING_OFF  0
#define TAB_OFF   98304
#define LDS_TOTAL 163840

#define VMCNT2() asm volatile("s_waitcnt vmcnt(2)" ::: "memory")
#define VMCNT0() asm volatile("s_waitcnt vmcnt(0)" ::: "memory")
#define LGKM0()  asm volatile("s_waitcnt lgkmcnt(0)" ::: "memory")
#define SCHED0() __builtin_amdgcn_sched_barrier(0)
#define SBAR()   __builtin_amdgcn_s_barrier()

typedef const __attribute__((address_space(1))) uint32_t  glb_u32;
typedef __attribute__((address_space(3))) uint32_t        lds_u32;

// round-to-nearest-even f32 -> bf16 (positive normal probs)
__device__ __forceinline__ uint32_t f2bf(float f) {
    uint32_t u = __float_as_uint(f);
    return (u + 0x7fffu + ((u >> 16) & 1u)) >> 16;
}
__device__ __forceinline__ float blo(uint32_t u) { return __uint_as_float(u << 16); }
__device__ __forceinline__ float bhi(uint32_t u) { return __uint_as_float(u & 0xffff0000u); }

// DMA one quarter (256 rows x 128 B) into ring slot q%3. Wave w stages its
// OWN rows [w*16, w*16+16): 2 insts x (8 rows x full 128-B span), fully
// LINEAR on both sides (no swizzle needed: the fused pass reads col-wise,
// which is bank-clean in a row-major buffer). Slot regions are wave-local
// on both produce and consume sides -> no cross-wave LDS hazards.
__device__ __forceinline__ void stage_quarter(const float* __restrict__ W, char* smem,
                                              int q, int bid, int w, int l) {
    const int slot = (q % 3) * 32768;
    const int col0 = bid * (NMAC * MACW) + (q >> 2) * MACW;    // floats
    const int r0   = (q & 3) * QROWS + w * 16 + (l >> 3);
    const float* g0 = W + ((size_t)r0 << 16) + col0 + (l & 7) * 4;
    const float* g1 = W + ((size_t)(r0 + 8) << 16) + col0 + (l & 7) * 4;
    __builtin_amdgcn_global_load_lds((glb_u32*)g0, (lds_u32*)(smem + RING_OFF + slot + w * 2048 + l * 16),        16, 0, 0);
    __builtin_amdgcn_global_lds:
    ;
}

// (placeholder label removed below -- full definition follows)
#undef RING_OFF
#define RING_OFF 0

__device__ __forceinline__ void stage_quarter2(const float* __restrict__ W, char* smem,
                                               int q, int bid, int w, int l) {
    const int slot = (q % 3) * 32768;
    const int col0 = bid * (NMAC * MACW) + (q >> 2) * MACW;    // floats
    const int r0   = (q & 3) * QROWS + w * 16 + (l >> 3);
    const float* g0 = W + ((size_t)r0 << 16) + col0 + (l & 7) * 4;
    const float* g1 = W + ((size_t)(r0 + 8) << 16) + col0 + (l & 7) * 4;
    __builtin_amdgcn_global_load_lds((glb_u32*)g0,
        (lds_u32*)(smem + RING_OFF + slot + w * 2048 + l * 16), 16, 0, 0);
    __builtin_amdgcn_global_load_lds((glb_u32*)g1,
        (lds_u32*)(smem + RING_OFF + slot + w * 2048 + 1024 + l * 16), 16, 0, 0);
}

// compute phase: 2 queries x 4 granules x 8 cols (verbatim R5 layout)
#define COMPUTE_PHASE()                                                                           \
    _Pragma("unroll")                                                                             \
    for (int g16 = 0; g16 < 4; ++g16) {                                                           \
        const int gb = g16 << 4;                                                                  \
        {                                                                                         \
            const uint4 va = *(const uint4*)(smem + TAB_OFF + baseb[0][0] + (gb ^ swzb[0][0]));   \
            const uint4 vb = *(const uint4*)(smem + TAB_OFF + baseb[0][1] + (gb ^ swzb[0][1]));   \
            const uint4 vc = *(const uint4*)(smem + TAB_OFF + baseb[0][2] + (gb ^ swzb[0][2]));   \
            acc0 = fmaf(blo(va.x) * blo(vb.x), blo(vc.x), acc0);                                  \
            acc0 = fmaf(bhi(va.x) * bhi(vb.x), bhi(vc.x), acc0);                                  \
            acc0 = fmaf(blo(va.y) * blo(vb.y), blo(vc.y), acc0);                                  \
            acc0 = fmaf(bhi(va.y) * bhi(vb.y), bhi(vc.y), acc0);                                  \
            acc0 = fmaf(blo(va.z) * blo(vb.z), blo(vc.z), acc0);                                  \
            acc0 = fmaf(bhi(va.z) * bhi(vb.z), bhi(vc.z), acc0);                                  \
            acc0 = fmaf(blo(va.w) * blo(vb.w), blo(vc.w), acc0);                                  \
            acc0 = fmaf(bhi(va.w) * bhi(vb.w), bhi(vc.w), acc0);                                  \
        }                                                                                         \
        {                                                                                         \
            const uint4 va = *(const uint4*)(smem + TAB_OFF + baseb[1][0] + (gb ^ swzb[1][0]));   \
            const uint4 vb = *(const uint4*)(smem + TAB_OFF + baseb[1][1] + (gb ^ swzb[1][1]));   \
            const uint4 vc = *(const uint4*)(smem + TAB_OFF + baseb[1][2] + (gb ^ swzb[1][2]));   \
            acc1 = fmaf(blo(va.x) * blo(vb.x), blo(vc.x), acc1);                                  \
            acc1 = fmaf(bhi(va.x) * bhi(vb.x), bhi(vc.x), acc1);                                  \
            acc1 = fmaf(blo(va.y) * blo(vb.y), blo(vc.y), acc1);                                  \
            acc1 = fmaf(bhi(va.y) * bhi(vb.y), bhi(vc.y), acc1);                                  \
            acc1 = fmaf(blo(va.z) * blo(vb.z), blo(vc.z), acc1);                                  \
            acc1 = fmaf(bhi(va.z) * bhi(vb.z), bhi(vc.z), acc1);                                  \
            acc1 = fmaf(blo(va.w) * blo(vb.w), blo(vc.w), acc1);                                  \
            acc1 = fmaf(bhi(va.w) * bhi(vb.w), bhi(vc.w), acc1);                                  \
        }                                                                                         \
    }

template<bool ATOMIC>
__global__ __launch_bounds__(TPB, 4) void rap_main(const float* __restrict__ W,
                                                   const int* __restrict__ qidx,
                                                   float* __restrict__ outp) {
    extern __shared__ char smem[];
    const int tid = threadIdx.x;
    const int bid = blockIdx.x;
    const int w = tid >> 6, l = tid & 63;

    // ---- per-thread query constants (2 queries/thread) ----
    const int q0 = tid * 2;
    int baseb[2][K_DIM];   // d*64 : byte base of table row
    int swzb[2][K_DIM];    // ((d>>1)&3)<<4 : granule XOR key in bytes
#pragma unroll
    for (int qq = 0; qq < 2; ++qq) {
#pragma unroll
        for (int k = 0; k < K_DIM; ++k) {
            const int d = qidx[(q0 + qq) * K_DIM + k];
            baseb[qq][k] = d << 6;
            swzb[qq][k]  = ((d >> 1) & 3) << 4;
        }
    }

    // ---- fused-pass mapping: lane -> (col, even/odd row half) ----
    const int c = l & 31;            // macro col 0..31
    const int h = l >> 5;            // 0 = even rows, 1 = odd rows

    float acc0 = 0.f, acc1 = 0.f;

    // drain qidx loads so vmcnt counts only stage DMAs; prefill ring
    VMCNT0(); SCHED0();
    stage_quarter2(W, smem, 0, bid, w, l);
    stage_quarter2(W, smem, 1, bid, w, l);

    for (int m = 0; m < NMAC; ++m) {
#pragma unroll
        for (int s = 0; s < 4; ++s) {
            const int q = m * 4 + s;
            if (q == NQT - 1) { VMCNT0(); } else { VMCNT2(); }
            SCHED0();

            // issue 2-ahead FIRST: in-flight stays at 4 insts through the pass.
            // slot (q+2)%3 == slot of q-1, whose (wave-local) reads retired
            // when this wave consumed its exps last iteration.
            if (q + 2 < NQT) stage_quarter2(W, smem, q + 2, bid, w, l);
            SCHED0();

            // ---- fused softmax: exp once, shfl denominator, col-wise u16 write ----
            {
                const char* p = smem + RING_OFF + (q % 3) * 32768
                                + (w * 16 + h) * 128 + c * 4;
                float e[8]; float sum = 0.f;
#pragma unroll
                for (int j = 0; j < 8; ++j) {           // rows h, h+2, .., h+14
                    e[j] = __expf(*(const float*)(p + j * 256));
                    sum += e[j];
                }
                sum += __shfl_xor(sum, 32);             // combine even+odd halves
                const float rec = __builtin_amdgcn_rcpf(sum);
                const int rbase = s * 256 + w * 16 + h;
#pragma unroll
                for (int j = 0; j < 8; ++j) {
                    const int row = rbase + 2 * j;
                    const uint32_t bf = f2bf(e[j] * rec);
                    *(uint16_t*)(smem + TAB_OFF + row * 64
                                 + ((((c >> 3) ^ ((row >> 1) & 3))) << 4)
                                 + ((c & 7) << 1)) = (uint16_t)bf;
                }
            }
        }

        LGKM0(); SCHED0(); SBAR(); SCHED0();   // table published

        COMPUTE_PHASE();

        LGKM0(); SCHED0(); SBAR(); SCHED0();   // table consumed -> free for next macro
    }

    if (ATOMIC) {
        atomicAdd(outp + q0,     acc0 * (1.0f / N_DIM));
        atomicAdd(outp + q0 + 1, acc1 * (1.0f / N_DIM));
    } else {
        // transposed partials [q][bid] so the reduce reads contiguously
        outp[(size_t)q0 * NBLK + bid]       = acc0;
        outp[(size_t)(q0 + 1) * NBLK + bid] = acc1;
    }
}

// 256 blocks x 256 threads; each wave reduces 2 queries (256 contiguous f32 each)
__global__ __launch_bounds__(256) void rap_reduce(const float* __restrict__ partials,
                                                  float* __restrict__ outp) {
    const int wv = threadIdx.x >> 6;
    const int l  = threadIdx.x & 63;
    const int qb = blockIdx.x * 8 + wv * 2;
#pragma unroll
    for (int i = 0; i < 2; ++i) {
        const int q = qb + i;
        const float* p = partials + (size_t)q * NBLK;
        float s = p[l] + p[l + 64] + p[l + 128] + p[l + 192];
        s += __shfl_xor(s, 1);
        s += __shfl_xor(s, 2);
        s += __shfl_xor(s, 4);
        s += __shfl_xor(s, 8);
        s += __shfl_xor(s, 16);
        s += __shfl_xor(s, 32);
        if (l == 0) outp[q] = s * (1.0f / N_DIM);
    }
}

extern "C" void kernel_launch(void* const* d_in, const int* in_sizes, int n_in,
                              void* d_out, int out_size, void* d_ws, size_t ws_size,
                              hipStream_t stream) {
    const float* W    = (const float*)d_in[0];
    const int*   qidx = (const int*)d_in[1];
    float*       outp = (float*)d_out;

    const size_t need = (size_t)Q_DIM * NBLK * sizeof(float);
    if (ws_size >= need) {
        (void)hipFuncSetAttribute((const void*)rap_main<false>,
                                  hipFuncAttributeMaxDynamicSharedMemorySize, LDS_TOTAL);
        float* partials = (float*)d_ws;
        hipLaunchKernelGGL(rap_main<false>, dim3(NBLK), dim3(TPB), LDS_TOTAL, stream,
                           W, qidx, partials);
        hipLaunchKernelGGL(rap_reduce, dim3(Q_DIM / 8), dim3(256), 0, stream,
                           partials, outp);
    } else {
        (void)hipFuncSetAttribute((const void*)rap_main<true>,
                                  hipFuncAttributeMaxDynamicSharedMemorySize, LDS_TOTAL);
        (void)hipMemsetAsync(d_out, 0, Q_DIM * sizeof(float), stream);
        hipLaunchKernelGGL(rap_main<true>, dim3(NBLK), dim3(TPB), LDS_TOTAL, stream,
                           W, qidx, outp);
    }
}